// Round 13
// baseline (135.162 us; speedup 1.0000x reference)
//
#include <hip/hip_runtime.h>

#define N_TOK 2048
#define DMODEL 1024
#define NH 16
#define NKV 4
#define HDIM 64
#define SCALE_LOG2E 0.1803368801111204f  // (1/8) * log2(e)

typedef __attribute__((ext_vector_type(8))) short short8;
typedef __attribute__((ext_vector_type(4))) float f32x4;
typedef __attribute__((ext_vector_type(16))) float f32x16;
typedef __attribute__((ext_vector_type(2))) int i32x2;
typedef __attribute__((ext_vector_type(4))) unsigned int u32x4;
typedef unsigned short u16;
typedef unsigned int u32;

__device__ __forceinline__ u16 f2bf(float x) {
    u32 u = __float_as_uint(x);
    u += 0x7FFF + ((u >> 16) & 1);   // round-to-nearest-even
    return (u16)(u >> 16);
}
__device__ __forceinline__ u32 pack2(float a, float b) {
    return (u32)f2bf(a) | ((u32)f2bf(b) << 16);
}
// pack high halves (truncating bf16) of two floats: [bf(a) | bf(b)<<16]
__device__ __forceinline__ u32 pack2t(float a, float b) {
    return __builtin_amdgcn_perm(__float_as_uint(b), __float_as_uint(a), 0x07060302u);
}

// ---------------------------------------------------------------------------
// prep: grid (32,16,5).
// z=0..2: W (K x NC) -> FB fragment-packed (direct MFMA B-operand streams):
//   FB[(((nt*16+it)*2+c)*4+n16)*512 + quad*128 + l15*8 + jj]
//     = bf16(W[k = it*64 + c*32 + quad*8 + jj][n = nt*64 + n16*16 + l15])
// z=3: Wo -> row-major transposed Wot (for gemm_out, unchanged path).
// z=4: x -> FA fragment-packed (direct MFMA A-operand streams):
//   FA[(((mt*16+it)*2+c)*4+m16)*512 + quad*128 + l15*8 + jj]
//     = bf16(x[m = mt*64 + m16*16 + l15][k = it*64 + c*32 + quad*8 + jj])
// ---------------------------------------------------------------------------
__global__ __launch_bounds__(256) void prep(
    const float* __restrict__ Wq, const float* __restrict__ Wk,
    const float* __restrict__ Wv, const float* __restrict__ Wo,
    const float* __restrict__ x,
    u16* __restrict__ FBq, u16* __restrict__ FBk, u16* __restrict__ FBv,
    u16* __restrict__ Wot, u16* __restrict__ FA)
{
    const int z = blockIdx.z;
    const int t = threadIdx.x;
    __shared__ float T[64][68];

    if (z == 4) {
        // ---- x -> FA ----
        const int mt = blockIdx.x, it = blockIdx.y;
        const int row = t >> 2, cs = (t & 3) * 16;
#pragma unroll
        for (int i = 0; i < 4; ++i)
            *(float4*)&T[row][cs + i * 4] =
                *(const float4*)(x + (size_t)(mt * 64 + row) * DMODEL + it * 64 + cs + i * 4);
        __syncthreads();
        const int ch = t >> 5, tsub = t & 31;
        const int cc = ch >> 2, mm = ch & 3;
        const int kl = cc * 32 + (tsub >> 3) * 8;
        const int ml0 = mm * 16 + (tsub & 7) * 2;
        u32 pk[8];
#pragma unroll
        for (int o = 0; o < 4; ++o)
            pk[o] = pack2(T[ml0][kl + 2 * o], T[ml0][kl + 2 * o + 1]);
#pragma unroll
        for (int o = 0; o < 4; ++o)
            pk[4 + o] = pack2(T[ml0 + 1][kl + 2 * o], T[ml0 + 1][kl + 2 * o + 1]);
        u16* dst = FA + (((size_t)(mt * 16 + it) * 2 + cc) * 4 + mm) * 512 + tsub * 16;
        uint4 w0; w0.x = pk[0]; w0.y = pk[1]; w0.z = pk[2]; w0.w = pk[3];
        uint4 w1; w1.x = pk[4]; w1.y = pk[5]; w1.z = pk[6]; w1.w = pk[7];
        *(uint4*)(dst) = w0;
        *(uint4*)(dst + 8) = w1;
        return;
    }

    if (z == 3) {
        // ---- Wo -> row-major Wot (unchanged path) ----
        const int n0 = blockIdx.x * 64;
        if (n0 >= 1024) return;
        const int k0 = blockIdx.y * 64;
        const int row = t >> 2, cs = (t & 3) * 16;
#pragma unroll
        for (int i = 0; i < 4; ++i)
            *(float4*)&T[row][cs + i * 4] =
                *(const float4*)(Wo + (size_t)(k0 + row) * 1024 + n0 + cs + i * 4);
        __syncthreads();
        const int nl = t >> 2, ks = (t & 3) * 16;
        u32 pk[8];
#pragma unroll
        for (int i = 0; i < 8; ++i)
            pk[i] = pack2(T[ks + 2 * i][nl], T[ks + 2 * i + 1][nl]);
        u16* dst = Wot + (size_t)(n0 + nl) * DMODEL + k0 + ks;
        uint4 w0; w0.x = pk[0]; w0.y = pk[1]; w0.z = pk[2]; w0.w = pk[3];
        uint4 w1; w1.x = pk[4]; w1.y = pk[5]; w1.z = pk[6]; w1.w = pk[7];
        *(uint4*)(dst) = w0;
        *(uint4*)(dst + 8) = w1;
        return;
    }

    // ---- W -> FB (z = 0,1,2) ----
    const float* W; u16* FB; int NC;
    if      (z == 0) { W = Wq; FB = FBq; NC = 1024; }
    else if (z == 1) { W = Wk; FB = FBk; NC = 256; }
    else             { W = Wv; FB = FBv; NC = 256; }
    const int nt = blockIdx.x, it = blockIdx.y;
    if (nt * 64 >= NC) return;
    const int row = t >> 2, cs = (t & 3) * 16;
#pragma unroll
    for (int i = 0; i < 4; ++i)
        *(float4*)&T[row][cs + i * 4] =
            *(const float4*)(W + (size_t)(it * 64 + row) * NC + nt * 64 + cs + i * 4);
    __syncthreads();
    const int ch = t >> 5, tsub = t & 31;
    const int cc = ch >> 2, nn = ch & 3;
    const int kl = cc * 32 + (tsub >> 3) * 8;
    const int nl0 = nn * 16 + (tsub & 7) * 2;
    u32 pk[8];
#pragma unroll
    for (int o = 0; o < 4; ++o)
        pk[o] = pack2(T[kl + 2 * o][nl0], T[kl + 2 * o + 1][nl0]);
#pragma unroll
    for (int o = 0; o < 4; ++o)
        pk[4 + o] = pack2(T[kl + 2 * o][nl0 + 1], T[kl + 2 * o + 1][nl0 + 1]);
    u16* dst = FB + (((size_t)(nt * 16 + it) * 2 + cc) * 4 + nn) * 512 + tsub * 16;
    uint4 w0; w0.x = pk[0]; w0.y = pk[1]; w0.z = pk[2]; w0.w = pk[3];
    uint4 w1; w1.x = pk[4]; w1.y = pk[5]; w1.z = pk[6]; w1.w = pk[7];
    *(uint4*)(dst) = w0;
    *(uint4*)(dst + 8) = w1;
}

// ---------------------------------------------------------------------------
// QKV GEMM: LDS-FREE, BARRIER-FREE. Both operands pre-fragment-packed (FA/FB)
// by prep; each wave streams its MFMA fragments directly from global/L2 as
// contiguous 1KB coalesced loads with a register double-buffer (distance 1,
// static names). 4 waves of 32x32 per 64x64 tile. grid (32,24) = 768 blocks.
// by<16 -> Q (rope, x SCALE_LOG2E, row-major out); 16..19 -> K -> FK;
// 20..23 -> V -> FV2 (layouts unchanged from r12):
//   FK[((((((kvh*2+khalf)*16+rd)*2+kg)*4+s)*2+hi)*32+l31)*8+j]
//   FV2[((((((g*16+keyblk)*4+kg)*2+kstep)*2+dgrp)*2+hi)*32+dl)*8+j]
// ---------------------------------------------------------------------------
__global__ __launch_bounds__(256, 3) void gemm_qkv(
    const u16* __restrict__ FA,
    const u16* __restrict__ FBq, const u16* __restrict__ FBk, const u16* __restrict__ FBv,
    u16* __restrict__ D0, u16* __restrict__ FKout, u16* __restrict__ FVout,
    const float* __restrict__ fc, const float* __restrict__ fs)
{
    const int t = threadIdx.x;
    const int mt = blockIdx.x;
    const int by = blockIdx.y;
    const int m0 = mt * 64;

    const u16* FB; int nt, nl0, ep;       // ep: 1 Q, 3 K->FK, 2 V->FV2
    float epsc = 1.f;
    if (by < 16)      { FB = FBq; nt = by;      nl0 = by * 64;        ep = 1;
                        epsc = SCALE_LOG2E; }
    else if (by < 20) { FB = FBk; nt = by - 16; nl0 = (by - 16) * 64; ep = 3; }
    else              { FB = FBv; nt = by - 20; nl0 = (by - 20) * 64; ep = 2; }

    const int w = t >> 6, lane = t & 63;
    const int quad = lane >> 4, l15 = lane & 15;
    const int wm = (w >> 1) * 32, wn = (w & 1) * 32;
    const int m16b = (w >> 1) * 2, n16b = (w & 1) * 2;

    const u16* fa = FA + (size_t)mt * 65536 + (size_t)m16b * 512 + (size_t)lane * 8;
    const u16* fb = FB + (size_t)nt * 65536 + (size_t)n16b * 512 + (size_t)lane * 8;

    f32x4 acc[2][2];
#pragma unroll
    for (int i = 0; i < 2; ++i)
#pragma unroll
        for (int j = 0; j < 2; ++j) acc[i][j] = {0.f, 0.f, 0.f, 0.f};

    short8 a0[2], b0[2], a1[2], b1[2];
#pragma unroll
    for (int i = 0; i < 2; ++i) a0[i] = *(const short8*)(fa + i * 512);
#pragma unroll
    for (int j = 0; j < 2; ++j) b0[j] = *(const short8*)(fb + j * 512);

    for (int st = 0; st < 32; st += 2) {
        if (st + 1 < 32) {
            const int off = (st + 1) * 2048;
#pragma unroll
            for (int i = 0; i < 2; ++i) a1[i] = *(const short8*)(fa + off + i * 512);
#pragma unroll
            for (int j = 0; j < 2; ++j) b1[j] = *(const short8*)(fb + off + j * 512);
        }
#pragma unroll
        for (int i = 0; i < 2; ++i)
#pragma unroll
            for (int j = 0; j < 2; ++j)
                acc[i][j] = __builtin_amdgcn_mfma_f32_16x16x32_bf16(a0[i], b0[j], acc[i][j], 0, 0, 0);
        if (st + 2 < 32) {
            const int off = (st + 2) * 2048;
#pragma unroll
            for (int i = 0; i < 2; ++i) a0[i] = *(const short8*)(fa + off + i * 512);
#pragma unroll
            for (int j = 0; j < 2; ++j) b0[j] = *(const short8*)(fb + off + j * 512);
        }
        if (st + 1 < 32) {
#pragma unroll
            for (int i = 0; i < 2; ++i)
#pragma unroll
                for (int j = 0; j < 2; ++j)
                    acc[i][j] = __builtin_amdgcn_mfma_f32_16x16x32_bf16(a1[i], b1[j], acc[i][j], 0, 0, 0);
        }
    }

#pragma unroll
    for (int i = 0; i < 2; ++i)
#pragma unroll
        for (int j = 0; j < 2; ++j) {
            const int cl = nl0 + wn + j * 16 + l15;
            if (ep == 1) {
#pragma unroll
                for (int r4 = 0; r4 < 4; ++r4) {
                    const int r = m0 + wm + i * 16 + quad * 4 + r4;
                    float own = acc[i][j][r4];
                    float other = __shfl_xor(own, 1, 64);
                    const int p = (cl & 63) >> 1;
                    const float c = fc[r * 32 + p] * epsc, s = fs[r * 32 + p] * epsc;
                    float outv = ((cl & 1) == 0) ? (own * c - other * s)
                                                 : (other * s + own * c);
                    D0[(size_t)r * 1024 + cl] = f2bf(outv);
                }
            } else if (ep == 3) {
                // K: rope, then fragment-packed FK store
#pragma unroll
                for (int r4 = 0; r4 < 4; ++r4) {
                    const int r = m0 + wm + i * 16 + quad * 4 + r4;
                    float own = acc[i][j][r4];
                    float other = __shfl_xor(own, 1, 64);
                    const int p = (cl & 63) >> 1;
                    const float c = fc[r * 32 + p], s = fs[r * 32 + p];
                    float outv = ((cl & 1) == 0) ? (own * c - other * s)
                                                 : (other * s + own * c);
                    const int kvh2 = cl >> 6, d = cl & 63;
                    const int s2 = d >> 4, hi2 = (d >> 3) & 1, jv = d & 7;
                    const int kh2 = r >> 10, rd2 = (r >> 6) & 15;
                    const int kg2 = (r >> 5) & 1, l31v = r & 31;
                    size_t idx = ((((((size_t)(kvh2 * 2 + kh2) * 16 + rd2) * 2 + kg2)
                                    * 4 + s2) * 2 + hi2) * 32 + l31v) * 8 + jv;
                    FKout[idx] = f2bf(outv);
                }
            } else {
                // V: packed 4-key store: r4=0..3 are consecutive jv in FV2
                const int rb = m0 + wm + i * 16 + quad * 4;
                const int g = cl >> 6, d = cl & 63;
                const int d2 = d >> 5, dl = d & 31;
                const int keyblk = rb >> 7, kg = (rb >> 5) & 3;
                const int kst = (rb >> 4) & 1, hb = (rb >> 3) & 1, jv = rb & 7;
                size_t idx = ((((((size_t)(g * 16 + keyblk) * 4 + kg) * 2 + kst) * 2 + d2)
                               * 2 + hb) * 32 + dl) * 8 + jv;
                uint2 pk;
                pk.x = pack2(acc[i][j][0], acc[i][j][1]);
                pk.y = pack2(acc[i][j][2], acc[i][j][3]);
                *(uint2*)(FVout + idx) = pk;
            }
        }
}

// ---------------------------------------------------------------------------
// Output GEMM: 3-buffer counted-vmcnt gload_lds structure (unchanged, r9).
// grid (32,16) = 512 blocks -> 2 blocks/CU even.
// ---------------------------------------------------------------------------
__device__ __forceinline__ void gload16(const u16* g, u16* l) {
    __builtin_amdgcn_global_load_lds(
        (const __attribute__((address_space(1))) unsigned int*)g,
        (__attribute__((address_space(3))) unsigned int*)l, 16, 0, 0);
}

__global__ __launch_bounds__(256, 2) void gemm_out(
    const u16* __restrict__ A, const u16* __restrict__ Bt, float* __restrict__ Dout)
{
    __shared__ u16 As[3][64][64];
    __shared__ u16 Bs[3][64][64];
    const int t = threadIdx.x;
    const int m0 = blockIdx.x * 64;
    const int nl0 = blockIdx.y * 64;

    const int w = t >> 6, lane = t & 63;
    const int quad = lane >> 4, l15 = lane & 15;
    const int wm = (w >> 1) * 32, wn = (w & 1) * 32;
    const int rx = l15 & 7;

    const int sro = w * 16 + (lane >> 3);
    const int sco = ((lane & 7) ^ (lane >> 3)) * 8;
    const u16* ApL = A + (size_t)(m0 + sro) * DMODEL + sco;
    const u16* BpL = Bt + (size_t)(nl0 + sro) * DMODEL + sco;

    f32x4 acc[2][2];
#pragma unroll
    for (int i = 0; i < 2; ++i)
#pragma unroll
        for (int j = 0; j < 2; ++j) acc[i][j] = {0.f, 0.f, 0.f, 0.f};

#pragma unroll
    for (int k = 0; k < 2; ++k) {
        gload16(ApL + k * 8 * DMODEL, &As[0][w * 16 + k * 8][0]);
        gload16(BpL + k * 8 * DMODEL, &Bs[0][w * 16 + k * 8][0]);
    }
#pragma unroll
    for (int k = 0; k < 2; ++k) {
        gload16(ApL + k * 8 * DMODEL + 64, &As[1][w * 16 + k * 8][0]);
        gload16(BpL + k * 8 * DMODEL + 64, &Bs[1][w * 16 + k * 8][0]);
    }
    asm volatile("s_waitcnt vmcnt(4)" ::: "memory");
    __builtin_amdgcn_sched_barrier(0);
    __builtin_amdgcn_s_barrier();

    int cb = 0, nb = 1, pb = 2;
    for (int it = 0; it < 16; ++it) {
        if (it + 2 < 16) {
            const int kk = (it + 2) * 64;
#pragma unroll
            for (int k = 0; k < 2; ++k) {
                gload16(ApL + k * 8 * DMODEL + kk, &As[pb][w * 16 + k * 8][0]);
                gload16(BpL + k * 8 * DMODEL + kk, &Bs[pb][w * 16 + k * 8][0]);
            }
        }
#pragma unroll
        for (int c = 0; c < 2; ++c) {
            short8 af[2], bf[2];
#pragma unroll
            for (int i = 0; i < 2; ++i)
                af[i] = *(const short8*)&As[cb][wm + i * 16 + l15][((4 * c + quad) ^ rx) * 8];
#pragma unroll
            for (int j = 0; j < 2; ++j)
                bf[j] = *(const short8*)&Bs[cb][wn + j * 16 + l15][((4 * c + quad) ^ rx) * 8];
#pragma unroll
            for (int i = 0; i < 2; ++i)
#pragma unroll
                for (int j = 0; j < 2; ++j)
                    acc[i][j] = __builtin_amdgcn_mfma_f32_16x16x32_bf16(af[i], bf[j], acc[i][j], 0, 0, 0);
        }
        if (it + 2 < 16) asm volatile("s_waitcnt vmcnt(4)" ::: "memory");
        else             asm volatile("s_waitcnt vmcnt(0)" ::: "memory");
        __builtin_amdgcn_sched_barrier(0);
        __builtin_amdgcn_s_barrier();
        const int tmp = cb; cb = nb; nb = pb; pb = tmp;
    }

#pragma unroll
    for (int i = 0; i < 2; ++i)
#pragma unroll
        for (int j = 0; j < 2; ++j) {
            const int cl = nl0 + wn + j * 16 + l15;
#pragma unroll
            for (int r4 = 0; r4 < 4; ++r4) {
                const int r = m0 + wm + i * 16 + quad * 4 + r4;
                Dout[(size_t)r * 1024 + cl] = acc[i][j][r4];
            }
        }
}

// ---------------------------------------------------------------------------
// MFMA flash attention (unchanged from r12): 32x32x16, in-block key-split,
// barrier-free main loop, FK/FV fragment streams, permlane P-assembly,
// ones-column l, LDS merge epilogue. Grid (32,16), 4 waves, 2 blocks/CU.
// ---------------------------------------------------------------------------
__global__ __launch_bounds__(256, 2) void attn(
    const u16* __restrict__ Qb, const u16* __restrict__ FK,
    const u16* __restrict__ FV, u16* __restrict__ Ob)
{
    __shared__ float Xf[4160];   // Ox[2][32][64] (4096 f32) + Lx[64]

    const int t = threadIdx.x;
    const int n0 = blockIdx.x * 64;
    const int h = blockIdx.y, kvh = h >> 2;
    const int w = t >> 6, lane = t & 63;
    const int hi = lane >> 5, l31 = lane & 31;
    const int qgrp = w & 1, khalf = w >> 1;

    const short8 ones = {(short)0x3F80, (short)0x3F80, (short)0x3F80, (short)0x3F80,
                         (short)0x3F80, (short)0x3F80, (short)0x3F80, (short)0x3F80};

    // Q B-frags: B[k=d][n=q], q = n0 + qgrp*32 + l31, d = s*16 + hi*8 + j
    const u16* qp = Qb + (size_t)(n0 + qgrp * 32 + l31) * (NH * HDIM) + h * HDIM + hi * 8;
    short8 qf[4];
#pragma unroll
    for (int s = 0; s < 4; ++s) qf[s] = *(const short8*)(qp + s * 16);

    // FK base for this wave's key half: + rd*4096 + kg*2048 + s*512 + lane*8
    const u16* fkb = FK + ((size_t)(kvh * 2 + khalf)) * 65536 + (size_t)lane * 8;
    const u16* fvb = FV + ((size_t)kvh) * 131072 + (size_t)lane * 8;

    f32x16 o[2], o_l;
#pragma unroll
    for (int d2 = 0; d2 < 2; ++d2)
#pragma unroll
        for (int r = 0; r < 16; ++r) o[d2][r] = 0.f;
#pragma unroll
    for (int r = 0; r < 16; ++r) o_l[r] = 0.f;

    // prologue: K frags for round 0, both kg (static names, rule #20)
    short8 kfa[4], kfb2[4];
#pragma unroll
    for (int s = 0; s < 4; ++s) kfa[s]  = *(const short8*)(fkb + s * 512);
#pragma unroll
    for (int s = 0; s < 4; ++s) kfb2[s] = *(const short8*)(fkb + 2048 + s * 512);

    for (int rd = 0; rd < 16; ++rd) {
        const int rdn = (rd + 1) & 15;   // wrap: dead prefetch on last round

        // ---- V frags for BOTH kg of this round (consumed after softmax) ----
        short8 vf[2][2][2];   // [kg][kstep][d2] -- fully unrolled, static idx
#pragma unroll
        for (int kg = 0; kg < 2; ++kg) {
            const int kg_global = khalf * 32 + rd * 2 + kg;
            const int keyblk = kg_global >> 2, kgi = kg_global & 3;
#pragma unroll
            for (int s = 0; s < 2; ++s)
#pragma unroll
                for (int d2 = 0; d2 < 2; ++d2)
                    vf[kg][s][d2] = *(const short8*)(fvb +
                        ((((size_t)keyblk * 4 + kgi) * 2 + s) * 2 + d2) * 512);
        }

        // ================= kg 0 =================
        f32x16 sa;
#pragma unroll
        for (int r = 0; r < 16; ++r) sa[r] = 0.f;
        __builtin_amdgcn_s_setprio(1);
#pragma unroll
        for (int s = 0; s < 4; ++s)
            sa = __builtin_amdgcn_mfma_f32_32x32x16_bf16(kfa[s], qf[s], sa, 0, 0, 0);
        __builtin_amdgcn_s_setprio(0);
        // prefetch kg0 K frags for next round (half-round distance to consume)
#pragma unroll
        for (int s = 0; s < 4; ++s)
            kfa[s] = *(const short8*)(fkb + (size_t)rdn * 4096 + s * 512);
        {
            float p[16];
#pragma unroll
            for (int r = 0; r < 16; ++r) p[r] = __builtin_amdgcn_exp2f(sa[r]);
            const u32 A0 = pack2t(p[0],  p[1]),  B0 = pack2t(p[2],  p[3]);
            const u32 C0 = pack2t(p[4],  p[5]),  D0 = pack2t(p[6],  p[7]);
            const u32 E0 = pack2t(p[8],  p[9]),  F0 = pack2t(p[10], p[11]);
            const u32 G0 = pack2t(p[12], p[13]), H0 = pack2t(p[14], p[15]);
            i32x2 X = __builtin_amdgcn_permlane32_swap((int)A0, (int)C0, false, false);
            i32x2 Y = __builtin_amdgcn_permlane32_swap((int)B0, (int)D0, false, false);
            i32x2 Z = __builtin_amdgcn_permlane32_swap((int)E0, (int)G0, false, false);
            i32x2 U = __builtin_amdgcn_permlane32_swap((int)F0, (int)H0, false, false);
            u32x4 t0 = {(u32)X.x, (u32)Y.x, (u32)X.y, (u32)Y.y};
            u32x4 t1 = {(u32)Z.x, (u32)U.x, (u32)Z.y, (u32)U.y};
            const short8 ap0 = __builtin_bit_cast(short8, t0);
            const short8 ap1 = __builtin_bit_cast(short8, t1);
            __builtin_amdgcn_s_setprio(1);
#pragma unroll
            for (int d2 = 0; d2 < 2; ++d2) {
                o[d2] = __builtin_amdgcn_mfma_f32_32x32x16_bf16(ap0, vf[0][0][d2], o[d2], 0, 0, 0);
                o[d2] = __builtin_amdgcn_mfma_f32_32x32x16_bf16(ap1, vf[0][1][d2], o[d2], 0, 0, 0);
            }
            o_l = __builtin_amdgcn_mfma_f32_32x32x16_bf16(ap0, ones, o_l, 0, 0, 0);
            o_l = __builtin_amdgcn_mfma_f32_32x32x16_bf16(ap1, ones, o_l, 0, 0, 0);
            __builtin_amdgcn_s_setprio(0);
        }

        // ================= kg 1 =================
#pragma unroll
        for (int r = 0; r < 16; ++r) sa[r] = 0.f;
        __builtin_amdgcn_s_setprio(1);
#pragma unroll
        for (int s = 0; s < 4; ++s)
            sa = __builtin_amdgcn_mfma_f32_32x32x16_bf16(kfb2[s], qf[s], sa, 0, 0, 0);
        __builtin_amdgcn_s_setprio(0);
        // prefetch kg1 K frags for next round
#pragma unroll
        for (int s = 0; s < 4; ++s)
            kfb2[s] = *(const short8*)(fkb + (size_t)rdn * 4096 + 2048 + s * 512);
        {
            float p[16];
#pragma unroll
            for (int r = 0; r < 16; ++r) p[r] = __builtin_amdgcn_exp2f(sa[r]);
            const u32 A0 = pack2t(p[0],  p[1]),  B0 = pack2t(p[2],  p[3]);
            const u32 C0 = pack2t(p[4],  p[5]),  D0 = pack2t(p[6],  p[7]);
            const u32 E0 = pack2t(p[8],  p[9]),  F0 = pack2t(p[10], p[11]);
            const u32 G0 = pack2t(p[12], p[13]), H0 = pack2t(p[14], p[15]);
            i32x2 X = __builtin_amdgcn_permlane32_swap((int)A0, (int)C0, false, false);
            i32x2 Y = __builtin_amdgcn_permlane32_swap((int)B0, (int)D0, false, false);
            i32x2 Z = __builtin_amdgcn_permlane32_swap((int)E0, (int)G0, false, false);
            i32x2 U = __builtin_amdgcn_permlane32_swap((int)F0, (int)H0, false, false);
            u32x4 t0 = {(u32)X.x, (u32)Y.x, (u32)X.y, (u32)Y.y};
            u32x4 t1 = {(u32)Z.x, (u32)U.x, (u32)Z.y, (u32)U.y};
            const short8 ap0 = __builtin_bit_cast(short8, t0);
            const short8 ap1 = __builtin_bit_cast(short8, t1);
            __builtin_amdgcn_s_setprio(1);
#pragma unroll
            for (int d2 = 0; d2 < 2; ++d2) {
                o[d2] = __builtin_amdgcn_mfma_f32_32x32x16_bf16(ap0, vf[1][0][d2], o[d2], 0, 0, 0);
                o[d2] = __builtin_amdgcn_mfma_f32_32x32x16_bf16(ap1, vf[1][1][d2], o[d2], 0, 0, 0);
            }
            o_l = __builtin_amdgcn_mfma_f32_32x32x16_bf16(ap0, ones, o_l, 0, 0, 0);
            o_l = __builtin_amdgcn_mfma_f32_32x32x16_bf16(ap1, ones, o_l, 0, 0, 0);
            __builtin_amdgcn_s_setprio(0);
        }
    }

    // ---- merge key halves through LDS and write bf16 ----
    if (khalf == 1) {
#pragma unroll
        for (int d2 = 0; d2 < 2; ++d2)
#pragma unroll
            for (int r = 0; r < 16; ++r) {
                const int q32 = (r & 3) + 8 * (r >> 2) + 4 * hi;
                Xf[qgrp * 2048 + q32 * 64 + d2 * 32 + l31] = o[d2][r];
            }
        if (l31 == 0) {
#pragma unroll
            for (int r = 0; r < 16; ++r) {
                const int q32 = (r & 3) + 8 * (r >> 2) + 4 * hi;
                Xf[4096 + qgrp * 32 + q32] = o_l[r];
            }
        }
    }
    __syncthreads();
    if (khalf == 0) {
        float linv[16];
#pragma unroll
        for (int r = 0; r < 16; ++r) {
            const int q32 = (r & 3) + 8 * (r >> 2) + 4 * hi;
            linv[r] = 1.f / (o_l[r] + Xf[4096 + qgrp * 32 + q32]);
        }
#pragma unroll
        for (int d2 = 0; d2 < 2; ++d2)
#pragma unroll
            for (int r = 0; r < 16; ++r) {
                const int q32 = (r & 3) + 8 * (r >> 2) + 4 * hi;
                const float val = o[d2][r] + Xf[qgrp * 2048 + q32 * 64 + d2 * 32 + l31];
                const int qrow = n0 + qgrp * 32 + q32;
                Ob[(size_t)qrow * (NH * HDIM) + h * HDIM + d2 * 32 + l31] = f2bf(val * linv[r]);
            }
    }
}

// ---------------------------------------------------------------------------
extern "C" void kernel_launch(void* const* d_in, const int* in_sizes, int n_in,
                              void* d_out, int out_size, void* d_ws, size_t ws_size,
                              hipStream_t stream) {
    const float* x  = (const float*)d_in[0];
    const float* fc = (const float*)d_in[1];
    const float* fs = (const float*)d_in[2];
    const float* Wq = (const float*)d_in[3];
    const float* Wk = (const float*)d_in[4];
    const float* Wv = (const float*)d_in[5];
    const float* Wo = (const float*)d_in[6];
    float* out = (float*)d_out;

    u16* ws  = (u16*)d_ws;
    u16* fa  = ws;                         // 2048*1024 (FA fragment-packed x)
    u16* fbq = fa  + (size_t)2048 * 1024;  // 1024*1024 (FB Wq)
    u16* fbk = fbq + (size_t)1024 * 1024;  // 256*1024  (FB Wk)
    u16* fbv = fbk + (size_t)256 * 1024;   // 256*1024  (FB Wv)
    u16* wot = fbv + (size_t)256 * 1024;   // 1024*1024 (row-major Wo^T)
    u16* qb  = wot + (size_t)1024 * 1024;  // 2048*1024
    u16* fk  = qb  + (size_t)2048 * 1024;  // 2048*256 (fragment-packed K)
    u16* fv  = fk  + (size_t)2048 * 256;   // 256*2048 (fragment-packed V, 32-wide)
    u16* aob = fv  + (size_t)256 * 2048;   // 2048*1024

    prep<<<dim3(32, 16, 5), dim3(256), 0, stream>>>(Wq, Wk, Wv, Wo, x,
                                                    fbq, fbk, fbv, wot, fa);
    gemm_qkv<<<dim3(32, 24), dim3(256), 0, stream>>>(fa, fbq, fbk, fbv,
                                                     qb, fk, fv, fc, fs);
    attn<<<dim3(32, 16), dim3(256), 0, stream>>>(qb, fk, fv, aob);
    gemm_out<<<dim3(32, 16), dim3(256), 0, stream>>>(aob, wot, out);
}

// Round 14
// 126.368 us; speedup vs baseline: 1.0696x; 1.0696x over previous
//
#include <hip/hip_runtime.h>

#define N_TOK 2048
#define DMODEL 1024
#define NH 16
#define NKV 4
#define HDIM 64
#define SCALE_LOG2E 0.1803368801111204f  // (1/8) * log2(e)

typedef __attribute__((ext_vector_type(8))) short short8;
typedef __attribute__((ext_vector_type(4))) float f32x4;
typedef __attribute__((ext_vector_type(16))) float f32x16;
typedef __attribute__((ext_vector_type(2))) int i32x2;
typedef __attribute__((ext_vector_type(4))) unsigned int u32x4;
typedef unsigned short u16;
typedef unsigned int u32;

__device__ __forceinline__ u16 f2bf(float x) {
    u32 u = __float_as_uint(x);
    u += 0x7FFF + ((u >> 16) & 1);   // round-to-nearest-even
    return (u16)(u >> 16);
}
__device__ __forceinline__ u32 pack2(float a, float b) {
    return (u32)f2bf(a) | ((u32)f2bf(b) << 16);
}
// pack high halves (truncating bf16) of two floats: [bf(a) | bf(b)<<16]
__device__ __forceinline__ u32 pack2t(float a, float b) {
    return __builtin_amdgcn_perm(__float_as_uint(b), __float_as_uint(a), 0x07060302u);
}

// async global->LDS, 16B/lane: HW writes lds_base + lane*16 (wave-uniform base).
__device__ __forceinline__ void gload16(const u16* g, u16* l) {
    __builtin_amdgcn_global_load_lds(
        (const __attribute__((address_space(1))) unsigned int*)g,
        (__attribute__((address_space(3))) unsigned int*)l, 16, 0, 0);
}

// ---------------------------------------------------------------------------
// prep: z=0..3 transpose W (K x NC) -> Wt (NC x K) bf16; z=4 convert x -> bf16
// ---------------------------------------------------------------------------
__global__ __launch_bounds__(256) void prep(
    const float* __restrict__ Wq, const float* __restrict__ Wk,
    const float* __restrict__ Wv, const float* __restrict__ Wo,
    const float* __restrict__ x,
    u16* __restrict__ Wqt, u16* __restrict__ Wkt, u16* __restrict__ Wvt,
    u16* __restrict__ Wot, u16* __restrict__ xb)
{
    const int z = blockIdx.z;
    const int t = threadIdx.x;
    if (z == 4) {
        size_t base = ((size_t)(blockIdx.y * 16 + blockIdx.x)) * 8192;
#pragma unroll
        for (int i = 0; i < 8; ++i) {
            float4 v = *(const float4*)(x + base + i * 1024 + t * 4);
            uint2 p; p.x = pack2(v.x, v.y); p.y = pack2(v.z, v.w);
            *(uint2*)(xb + base + i * 1024 + t * 4) = p;
        }
        return;
    }
    const float* W; u16* Wt; int NC;
    if      (z == 0) { W = Wq; Wt = Wqt; NC = 1024; }
    else if (z == 1) { W = Wk; Wt = Wkt; NC = 256; }
    else if (z == 2) { W = Wv; Wt = Wvt; NC = 256; }
    else             { W = Wo; Wt = Wot; NC = 1024; }
    const int n0 = blockIdx.x * 64;
    if (n0 >= NC) return;
    const int k0 = blockIdx.y * 64;
    __shared__ float T[64][68];
    const int row = t >> 2, cs = (t & 3) * 16;
#pragma unroll
    for (int i = 0; i < 4; ++i)
        *(float4*)&T[row][cs + i * 4] =
            *(const float4*)(W + (size_t)(k0 + row) * NC + n0 + cs + i * 4);
    __syncthreads();
    const int nl = t >> 2, ks = (t & 3) * 16;
    u32 pk[8];
#pragma unroll
    for (int i = 0; i < 8; ++i)
        pk[i] = pack2(T[ks + 2 * i][nl], T[ks + 2 * i + 1][nl]);
    u16* dst = Wt + (size_t)(n0 + nl) * DMODEL + k0 + ks;
    uint4 w0; w0.x = pk[0]; w0.y = pk[1]; w0.z = pk[2]; w0.w = pk[3];
    uint4 w1; w1.x = pk[4]; w1.y = pk[5]; w1.z = pk[6]; w1.w = pk[7];
    *(uint4*)(dst) = w0;
    *(uint4*)(dst + 8) = w1;
}

// ---------------------------------------------------------------------------
// QKV GEMM: tile 64x64, BK=64, gload_lds staging, 3-BUFFER RING with counted
// vmcnt (T4): prefetch distance 2; never vmcnt(0) in the main loop. Raw
// s_barrier. Both-sides XOR swizzle. 4 waves of 32x32.
// grid (32,24) = 768 blocks -> 3 blocks/CU (LDS 48 KB).
// by<16 -> Q (rope, x SCALE_LOG2E, row-major out);
// 16..19 -> K (rope) in FRAGMENT-PACKED FK layout (S^T A-operand order):
//   FK[((((((kvh*2+khalf)*16+rd)*2+kg)*4+s)*2+hi)*32+l31)*8+j]
//     = K[key = khalf*1024 + rd*64 + kg*32 + l31][d = s*16 + hi*8 + j]
// 20..23 -> V in FV2:
//   FV2[((((((g*16+keyblk)*4+kg)*2+kstep)*2+dgrp)*2+hi)*32+dl)*8+j]
//     = V[key = keyblk*128 + kg*32 + kstep*16 + hi*8 + j][d = dgrp*32 + dl]
// ---------------------------------------------------------------------------
__global__ __launch_bounds__(256, 3) void gemm_qkv(
    const u16* __restrict__ A,
    const u16* __restrict__ B0, const u16* __restrict__ B1, const u16* __restrict__ B2,
    u16* __restrict__ D0, u16* __restrict__ FKout, u16* __restrict__ FVout,
    const float* __restrict__ fc, const float* __restrict__ fs)
{
    __shared__ u16 As[3][64][64];   // linear: required by global_load_lds
    __shared__ u16 Bs[3][64][64];
    const int t = threadIdx.x;
    const int m0 = blockIdx.x * 64;
    const int by = blockIdx.y;

    const u16* Bt; int nl0, ep;           // ep: 1 Q, 3 K->FK, 2 V->FV2
    float epsc = 1.f;
    if (by < 16)      { Bt = B0; nl0 = by * 64;        ep = 1; epsc = SCALE_LOG2E; }
    else if (by < 20) { Bt = B1; nl0 = (by - 16) * 64; ep = 3; }
    else              { Bt = B2; nl0 = (by - 20) * 64; ep = 2; }

    const int w = t >> 6, lane = t & 63;
    const int quad = lane >> 4, l15 = lane & 15;
    const int wm = (w >> 1) * 32, wn = (w & 1) * 32;
    const int rx = l15 & 7;                         // read-side swizzle key

    // staging: wave w covers tile rows [w*16, w*16+16), 2 instrs x 8 rows each
    const int sro = w * 16 + (lane >> 3);           // per-lane staged row
    const int sco = ((lane & 7) ^ (lane >> 3)) * 8; // pre-swizzled source col
    const u16* ApL = A + (size_t)(m0 + sro) * DMODEL + sco;
    const u16* BpL = Bt + (size_t)(nl0 + sro) * DMODEL + sco;

    f32x4 acc[2][2];
#pragma unroll
    for (int i = 0; i < 2; ++i)
#pragma unroll
        for (int j = 0; j < 2; ++j) acc[i][j] = {0.f, 0.f, 0.f, 0.f};

    // prologue: tile 0 -> buf0, tile 1 -> buf1; wait tile0 (4 newest in flight)
#pragma unroll
    for (int k = 0; k < 2; ++k) {
        gload16(ApL + k * 8 * DMODEL, &As[0][w * 16 + k * 8][0]);
        gload16(BpL + k * 8 * DMODEL, &Bs[0][w * 16 + k * 8][0]);
    }
#pragma unroll
    for (int k = 0; k < 2; ++k) {
        gload16(ApL + k * 8 * DMODEL + 64, &As[1][w * 16 + k * 8][0]);
        gload16(BpL + k * 8 * DMODEL + 64, &Bs[1][w * 16 + k * 8][0]);
    }
    asm volatile("s_waitcnt vmcnt(4)" ::: "memory");
    __builtin_amdgcn_sched_barrier(0);
    __builtin_amdgcn_s_barrier();

    int cb = 0, nb = 1, pb = 2;    // current / next / prefetch buffer ids
    for (int it = 0; it < 16; ++it) {
        if (it + 2 < 16) {
            const int kk = (it + 2) * 64;
#pragma unroll
            for (int k = 0; k < 2; ++k) {
                gload16(ApL + k * 8 * DMODEL + kk, &As[pb][w * 16 + k * 8][0]);
                gload16(BpL + k * 8 * DMODEL + kk, &Bs[pb][w * 16 + k * 8][0]);
            }
        }
#pragma unroll
        for (int c = 0; c < 2; ++c) {
            short8 af[2], bf[2];
#pragma unroll
            for (int i = 0; i < 2; ++i)
                af[i] = *(const short8*)&As[cb][wm + i * 16 + l15][((4 * c + quad) ^ rx) * 8];
#pragma unroll
            for (int j = 0; j < 2; ++j)
                bf[j] = *(const short8*)&Bs[cb][wn + j * 16 + l15][((4 * c + quad) ^ rx) * 8];
#pragma unroll
            for (int i = 0; i < 2; ++i)
#pragma unroll
                for (int j = 0; j < 2; ++j)
                    acc[i][j] = __builtin_amdgcn_mfma_f32_16x16x32_bf16(af[i], bf[j], acc[i][j], 0, 0, 0);
        }
        // next tile (issued 2 iters back) must be drained; newest 4 may fly on
        if (it + 2 < 16) asm volatile("s_waitcnt vmcnt(4)" ::: "memory");
        else             asm volatile("s_waitcnt vmcnt(0)" ::: "memory");
        __builtin_amdgcn_sched_barrier(0);
        __builtin_amdgcn_s_barrier();
        const int tmp = cb; cb = nb; nb = pb; pb = tmp;
    }

#pragma unroll
    for (int i = 0; i < 2; ++i)
#pragma unroll
        for (int j = 0; j < 2; ++j) {
            const int cl = nl0 + wn + j * 16 + l15;
            if (ep == 1) {
#pragma unroll
                for (int r4 = 0; r4 < 4; ++r4) {
                    const int r = m0 + wm + i * 16 + quad * 4 + r4;
                    float own = acc[i][j][r4];
                    float other = __shfl_xor(own, 1, 64);
                    const int p = (cl & 63) >> 1;
                    const float c = fc[r * 32 + p] * epsc, s = fs[r * 32 + p] * epsc;
                    float outv = ((cl & 1) == 0) ? (own * c - other * s)
                                                 : (other * s + own * c);
                    D0[(size_t)r * 1024 + cl] = f2bf(outv);
                }
            } else if (ep == 3) {
                // K: rope, then fragment-packed FK store
#pragma unroll
                for (int r4 = 0; r4 < 4; ++r4) {
                    const int r = m0 + wm + i * 16 + quad * 4 + r4;
                    float own = acc[i][j][r4];
                    float other = __shfl_xor(own, 1, 64);
                    const int p = (cl & 63) >> 1;
                    const float c = fc[r * 32 + p], s = fs[r * 32 + p];
                    float outv = ((cl & 1) == 0) ? (own * c - other * s)
                                                 : (other * s + own * c);
                    const int kvh2 = cl >> 6, d = cl & 63;
                    const int s2 = d >> 4, hi2 = (d >> 3) & 1, jv = d & 7;
                    const int kh2 = r >> 10, rd2 = (r >> 6) & 15;
                    const int kg2 = (r >> 5) & 1, l31v = r & 31;
                    size_t idx = ((((((size_t)(kvh2 * 2 + kh2) * 16 + rd2) * 2 + kg2)
                                    * 4 + s2) * 2 + hi2) * 32 + l31v) * 8 + jv;
                    FKout[idx] = f2bf(outv);
                }
            } else {
                // V: packed 4-key store: r4=0..3 are consecutive jv in FV2
                const int rb = m0 + wm + i * 16 + quad * 4;
                const int g = cl >> 6, d = cl & 63;
                const int d2 = d >> 5, dl = d & 31;
                const int keyblk = rb >> 7, kg = (rb >> 5) & 3;
                const int kst = (rb >> 4) & 1, hb = (rb >> 3) & 1, jv = rb & 7;
                size_t idx = ((((((size_t)(g * 16 + keyblk) * 4 + kg) * 2 + kst) * 2 + d2)
                               * 2 + hb) * 32 + dl) * 8 + jv;
                uint2 pk;
                pk.x = pack2(acc[i][j][0], acc[i][j][1]);
                pk.y = pack2(acc[i][j][2], acc[i][j][3]);
                *(uint2*)(FVout + idx) = pk;
            }
        }
}

// ---------------------------------------------------------------------------
// Output GEMM: same 3-buffer counted-vmcnt structure, tile 64x64, fp32 out.
// grid (32,16) = 512 blocks -> 2 blocks/CU even.
// ---------------------------------------------------------------------------
__global__ __launch_bounds__(256, 2) void gemm_out(
    const u16* __restrict__ A, const u16* __restrict__ Bt, float* __restrict__ Dout)
{
    __shared__ u16 As[3][64][64];
    __shared__ u16 Bs[3][64][64];
    const int t = threadIdx.x;
    const int m0 = blockIdx.x * 64;
    const int nl0 = blockIdx.y * 64;

    const int w = t >> 6, lane = t & 63;
    const int quad = lane >> 4, l15 = lane & 15;
    const int wm = (w >> 1) * 32, wn = (w & 1) * 32;
    const int rx = l15 & 7;

    const int sro = w * 16 + (lane >> 3);
    const int sco = ((lane & 7) ^ (lane >> 3)) * 8;
    const u16* ApL = A + (size_t)(m0 + sro) * DMODEL + sco;
    const u16* BpL = Bt + (size_t)(nl0 + sro) * DMODEL + sco;

    f32x4 acc[2][2];
#pragma unroll
    for (int i = 0; i < 2; ++i)
#pragma unroll
        for (int j = 0; j < 2; ++j) acc[i][j] = {0.f, 0.f, 0.f, 0.f};

#pragma unroll
    for (int k = 0; k < 2; ++k) {
        gload16(ApL + k * 8 * DMODEL, &As[0][w * 16 + k * 8][0]);
        gload16(BpL + k * 8 * DMODEL, &Bs[0][w * 16 + k * 8][0]);
    }
#pragma unroll
    for (int k = 0; k < 2; ++k) {
        gload16(ApL + k * 8 * DMODEL + 64, &As[1][w * 16 + k * 8][0]);
        gload16(BpL + k * 8 * DMODEL + 64, &Bs[1][w * 16 + k * 8][0]);
    }
    asm volatile("s_waitcnt vmcnt(4)" ::: "memory");
    __builtin_amdgcn_sched_barrier(0);
    __builtin_amdgcn_s_barrier();

    int cb = 0, nb = 1, pb = 2;
    for (int it = 0; it < 16; ++it) {
        if (it + 2 < 16) {
            const int kk = (it + 2) * 64;
#pragma unroll
            for (int k = 0; k < 2; ++k) {
                gload16(ApL + k * 8 * DMODEL + kk, &As[pb][w * 16 + k * 8][0]);
                gload16(BpL + k * 8 * DMODEL + kk, &Bs[pb][w * 16 + k * 8][0]);
            }
        }
#pragma unroll
        for (int c = 0; c < 2; ++c) {
            short8 af[2], bf[2];
#pragma unroll
            for (int i = 0; i < 2; ++i)
                af[i] = *(const short8*)&As[cb][wm + i * 16 + l15][((4 * c + quad) ^ rx) * 8];
#pragma unroll
            for (int j = 0; j < 2; ++j)
                bf[j] = *(const short8*)&Bs[cb][wn + j * 16 + l15][((4 * c + quad) ^ rx) * 8];
#pragma unroll
            for (int i = 0; i < 2; ++i)
#pragma unroll
                for (int j = 0; j < 2; ++j)
                    acc[i][j] = __builtin_amdgcn_mfma_f32_16x16x32_bf16(af[i], bf[j], acc[i][j], 0, 0, 0);
        }
        if (it + 2 < 16) asm volatile("s_waitcnt vmcnt(4)" ::: "memory");
        else             asm volatile("s_waitcnt vmcnt(0)" ::: "memory");
        __builtin_amdgcn_sched_barrier(0);
        __builtin_amdgcn_s_barrier();
        const int tmp = cb; cb = nb; nb = pb; pb = tmp;
    }

#pragma unroll
    for (int i = 0; i < 2; ++i)
#pragma unroll
        for (int j = 0; j < 2; ++j) {
            const int cl = nl0 + wn + j * 16 + l15;
#pragma unroll
            for (int r4 = 0; r4 < 4; ++r4) {
                const int r = m0 + wm + i * 16 + quad * 4 + r4;
                Dout[(size_t)r * 1024 + cl] = acc[i][j][r4];
            }
        }
}

// ---------------------------------------------------------------------------
// MFMA flash attention, 32x32x16, IN-BLOCK key-split, BARRIER-FREE main loop:
// K read directly from global in fragment-packed FK layout; K frags
// prefetched one round ahead (static names); V frags at round start.
// P assembled in-register via v_permlane32_swap_b32 (T12). l via ones-column
// MFMA. One __syncthreads before the khalf-merge. bf16 out.
// Grid (32 qtiles, 16 heads) = 512 blocks, 4 waves, 2 blocks/CU.
// ---------------------------------------------------------------------------
__global__ __launch_bounds__(256, 2) void attn(
    const u16* __restrict__ Qb, const u16* __restrict__ FK,
    const u16* __restrict__ FV, u16* __restrict__ Ob)
{
    __shared__ float Xf[4160];   // Ox[2][32][64] (4096 f32) + Lx[64]

    const int t = threadIdx.x;
    const int n0 = blockIdx.x * 64;
    const int h = blockIdx.y, kvh = h >> 2;
    const int w = t >> 6, lane = t & 63;
    const int hi = lane >> 5, l31 = lane & 31;
    const int qgrp = w & 1, khalf = w >> 1;

    const short8 ones = {(short)0x3F80, (short)0x3F80, (short)0x3F80, (short)0x3F80,
                         (short)0x3F80, (short)0x3F80, (short)0x3F80, (short)0x3F80};

    const u16* qp = Qb + (size_t)(n0 + qgrp * 32 + l31) * (NH * HDIM) + h * HDIM + hi * 8;
    short8 qf[4];
#pragma unroll
    for (int s = 0; s < 4; ++s) qf[s] = *(const short8*)(qp + s * 16);

    const u16* fkb = FK + ((size_t)(kvh * 2 + khalf)) * 65536 + (size_t)lane * 8;
    const u16* fvb = FV + ((size_t)kvh) * 131072 + (size_t)lane * 8;

    f32x16 o[2], o_l;
#pragma unroll
    for (int d2 = 0; d2 < 2; ++d2)
#pragma unroll
        for (int r = 0; r < 16; ++r) o[d2][r] = 0.f;
#pragma unroll
    for (int r = 0; r < 16; ++r) o_l[r] = 0.f;

    short8 kfa[4], kfb2[4];
#pragma unroll
    for (int s = 0; s < 4; ++s) kfa[s]  = *(const short8*)(fkb + s * 512);
#pragma unroll
    for (int s = 0; s < 4; ++s) kfb2[s] = *(const short8*)(fkb + 2048 + s * 512);

    for (int rd = 0; rd < 16; ++rd) {
        const int rdn = (rd + 1) & 15;   // wrap: dead prefetch on last round

        short8 vf[2][2][2];   // [kg][kstep][d2] -- fully unrolled, static idx
#pragma unroll
        for (int kg = 0; kg < 2; ++kg) {
            const int kg_global = khalf * 32 + rd * 2 + kg;
            const int keyblk = kg_global >> 2, kgi = kg_global & 3;
#pragma unroll
            for (int s = 0; s < 2; ++s)
#pragma unroll
                for (int d2 = 0; d2 < 2; ++d2)
                    vf[kg][s][d2] = *(const short8*)(fvb +
                        ((((size_t)keyblk * 4 + kgi) * 2 + s) * 2 + d2) * 512);
        }

        // ================= kg 0 =================
        f32x16 sa;
#pragma unroll
        for (int r = 0; r < 16; ++r) sa[r] = 0.f;
        __builtin_amdgcn_s_setprio(1);
#pragma unroll
        for (int s = 0; s < 4; ++s)
            sa = __builtin_amdgcn_mfma_f32_32x32x16_bf16(kfa[s], qf[s], sa, 0, 0, 0);
        __builtin_amdgcn_s_setprio(0);
#pragma unroll
        for (int s = 0; s < 4; ++s)
            kfa[s] = *(const short8*)(fkb + (size_t)rdn * 4096 + s * 512);
        {
            float p[16];
#pragma unroll
            for (int r = 0; r < 16; ++r) p[r] = __builtin_amdgcn_exp2f(sa[r]);
            const u32 A0 = pack2t(p[0],  p[1]),  B0 = pack2t(p[2],  p[3]);
            const u32 C0 = pack2t(p[4],  p[5]),  D0 = pack2t(p[6],  p[7]);
            const u32 E0 = pack2t(p[8],  p[9]),  F0 = pack2t(p[10], p[11]);
            const u32 G0 = pack2t(p[12], p[13]), H0 = pack2t(p[14], p[15]);
            i32x2 X = __builtin_amdgcn_permlane32_swap((int)A0, (int)C0, false, false);
            i32x2 Y = __builtin_amdgcn_permlane32_swap((int)B0, (int)D0, false, false);
            i32x2 Z = __builtin_amdgcn_permlane32_swap((int)E0, (int)G0, false, false);
            i32x2 U = __builtin_amdgcn_permlane32_swap((int)F0, (int)H0, false, false);
            u32x4 t0 = {(u32)X.x, (u32)Y.x, (u32)X.y, (u32)Y.y};
            u32x4 t1 = {(u32)Z.x, (u32)U.x, (u32)Z.y, (u32)U.y};
            const short8 ap0 = __builtin_bit_cast(short8, t0);
            const short8 ap1 = __builtin_bit_cast(short8, t1);
            __builtin_amdgcn_s_setprio(1);
#pragma unroll
            for (int d2 = 0; d2 < 2; ++d2) {
                o[d2] = __builtin_amdgcn_mfma_f32_32x32x16_bf16(ap0, vf[0][0][d2], o[d2], 0, 0, 0);
                o[d2] = __builtin_amdgcn_mfma_f32_32x32x16_bf16(ap1, vf[0][1][d2], o[d2], 0, 0, 0);
            }
            o_l = __builtin_amdgcn_mfma_f32_32x32x16_bf16(ap0, ones, o_l, 0, 0, 0);
            o_l = __builtin_amdgcn_mfma_f32_32x32x16_bf16(ap1, ones, o_l, 0, 0, 0);
            __builtin_amdgcn_s_setprio(0);
        }

        // ================= kg 1 =================
#pragma unroll
        for (int r = 0; r < 16; ++r) sa[r] = 0.f;
        __builtin_amdgcn_s_setprio(1);
#pragma unroll
        for (int s = 0; s < 4; ++s)
            sa = __builtin_amdgcn_mfma_f32_32x32x16_bf16(kfb2[s], qf[s], sa, 0, 0, 0);
        __builtin_amdgcn_s_setprio(0);
#pragma unroll
        for (int s = 0; s < 4; ++s)
            kfb2[s] = *(const short8*)(fkb + (size_t)rdn * 4096 + 2048 + s * 512);
        {
            float p[16];
#pragma unroll
            for (int r = 0; r < 16; ++r) p[r] = __builtin_amdgcn_exp2f(sa[r]);
            const u32 A0 = pack2t(p[0],  p[1]),  B0 = pack2t(p[2],  p[3]);
            const u32 C0 = pack2t(p[4],  p[5]),  D0 = pack2t(p[6],  p[7]);
            const u32 E0 = pack2t(p[8],  p[9]),  F0 = pack2t(p[10], p[11]);
            const u32 G0 = pack2t(p[12], p[13]), H0 = pack2t(p[14], p[15]);
            i32x2 X = __builtin_amdgcn_permlane32_swap((int)A0, (int)C0, false, false);
            i32x2 Y = __builtin_amdgcn_permlane32_swap((int)B0, (int)D0, false, false);
            i32x2 Z = __builtin_amdgcn_permlane32_swap((int)E0, (int)G0, false, false);
            i32x2 U = __builtin_amdgcn_permlane32_swap((int)F0, (int)H0, false, false);
            u32x4 t0 = {(u32)X.x, (u32)Y.x, (u32)X.y, (u32)Y.y};
            u32x4 t1 = {(u32)Z.x, (u32)U.x, (u32)Z.y, (u32)U.y};
            const short8 ap0 = __builtin_bit_cast(short8, t0);
            const short8 ap1 = __builtin_bit_cast(short8, t1);
            __builtin_amdgcn_s_setprio(1);
#pragma unroll
            for (int d2 = 0; d2 < 2; ++d2) {
                o[d2] = __builtin_amdgcn_mfma_f32_32x32x16_bf16(ap0, vf[1][0][d2], o[d2], 0, 0, 0);
                o[d2] = __builtin_amdgcn_mfma_f32_32x32x16_bf16(ap1, vf[1][1][d2], o[d2], 0, 0, 0);
            }
            o_l = __builtin_amdgcn_mfma_f32_32x32x16_bf16(ap0, ones, o_l, 0, 0, 0);
            o_l = __builtin_amdgcn_mfma_f32_32x32x16_bf16(ap1, ones, o_l, 0, 0, 0);
            __builtin_amdgcn_s_setprio(0);
        }
    }

    // ---- merge key halves through LDS and write bf16 ----
    if (khalf == 1) {
#pragma unroll
        for (int d2 = 0; d2 < 2; ++d2)
#pragma unroll
            for (int r = 0; r < 16; ++r) {
                const int q32 = (r & 3) + 8 * (r >> 2) + 4 * hi;
                Xf[qgrp * 2048 + q32 * 64 + d2 * 32 + l31] = o[d2][r];
            }
        if (l31 == 0) {
#pragma unroll
            for (int r = 0; r < 16; ++r) {
                const int q32 = (r & 3) + 8 * (r >> 2) + 4 * hi;
                Xf[4096 + qgrp * 32 + q32] = o_l[r];
            }
        }
    }
    __syncthreads();
    if (khalf == 0) {
        float linv[16];
#pragma unroll
        for (int r = 0; r < 16; ++r) {
            const int q32 = (r & 3) + 8 * (r >> 2) + 4 * hi;
            linv[r] = 1.f / (o_l[r] + Xf[4096 + qgrp * 32 + q32]);
        }
#pragma unroll
        for (int d2 = 0; d2 < 2; ++d2)
#pragma unroll
            for (int r = 0; r < 16; ++r) {
                const int q32 = (r & 3) + 8 * (r >> 2) + 4 * hi;
                const float val = o[d2][r] + Xf[qgrp * 2048 + q32 * 64 + d2 * 32 + l31];
                const int qrow = n0 + qgrp * 32 + q32;
                Ob[(size_t)qrow * (NH * HDIM) + h * HDIM + d2 * 32 + l31] = f2bf(val * linv[r]);
            }
    }
}

// ---------------------------------------------------------------------------
extern "C" void kernel_launch(void* const* d_in, const int* in_sizes, int n_in,
                              void* d_out, int out_size, void* d_ws, size_t ws_size,
                              hipStream_t stream) {
    const float* x  = (const float*)d_in[0];
    const float* fc = (const float*)d_in[1];
    const float* fs = (const float*)d_in[2];
    const float* Wq = (const float*)d_in[3];
    const float* Wk = (const float*)d_in[4];
    const float* Wv = (const float*)d_in[5];
    const float* Wo = (const float*)d_in[6];
    float* out = (float*)d_out;

    u16* ws  = (u16*)d_ws;
    u16* xb  = ws;                         // 2048*1024
    u16* Wqt = xb  + (size_t)2048 * 1024;  // 1024*1024
    u16* Wkt = Wqt + (size_t)1024 * 1024;  // 256*1024
    u16* Wvt = Wkt + (size_t)256 * 1024;   // 256*1024
    u16* Wot = Wvt + (size_t)256 * 1024;   // 1024*1024
    u16* qb  = Wot + (size_t)1024 * 1024;  // 2048*1024
    u16* fk  = qb  + (size_t)2048 * 1024;  // 2048*256 (fragment-packed K)
    u16* fv  = fk  + (size_t)2048 * 256;   // 256*2048 (fragment-packed V, 32-wide)
    u16* aob = fv  + (size_t)256 * 2048;   // 2048*1024

    prep<<<dim3(16, 16, 5), dim3(256), 0, stream>>>(Wq, Wk, Wv, Wo, x,
                                                    Wqt, Wkt, Wvt, Wot, xb);
    gemm_qkv<<<dim3(32, 24), dim3(256), 0, stream>>>(xb, Wqt, Wkt, Wvt,
                                                     qb, fk, fv, fc, fs);
    attn<<<dim3(32, 16), dim3(256), 0, stream>>>(qb, fk, fv, aob);
    gemm_out<<<dim3(32, 16), dim3(256), 0, stream>>>(aob, Wot, out);
}